// Round 3
// baseline (374.531 us; speedup 1.0000x reference)
//
#include <hip/hip_runtime.h>

// Overlap-add reconstruction (inverse framing), MI355X / gfx950. Round 3.
//
// x: [B=16, FV=2000, FRAME=2048] fp32, HOP=512, PAD0=PAD1=768.
// out[b][o] = (1/cnt) * sum_{f} x[b][f][p-512f], p=o+PAD0, q=p>>9,
//   f in [max(0,q-3), min(FV-1,q)], cnt = #valid f.
// Pure gather, irreducible traffic: 256 MB read + 64 MB write -> BW-bound.
//
// R3 changes vs R2 (kernel est. ~91 us, 3.6 TB/s vs 52 us roofline):
//  - ITERS 2 -> 4: 16 loads in flight per thread before the adds drain them
//    (MLP was 8). Blocks 8000 -> 4000, still ~16/CU.
//  - Removed nt from LOADS: streaming reads gain nothing from bypassing L2
//    (lines fully consumed, no pollution to avoid) and may lose MSHR/merge
//    capacity. nt kept on stores (pure write-once stream).

#define FRAME   2048
#define HOP     512
#define NFV     2000
#define PAD0    768
#define OUT_PER_B (NFV * HOP)          // 1,024,000
#define IN_PER_B  (NFV * FRAME)        // 4,096,000
#define BLOCK   256
#define ITERS   4
#define GROUPS_PER_BLOCK (BLOCK * ITERS)            // 1024 groups = 4096 samples
#define GRID_X  (OUT_PER_B / 4 / GROUPS_PER_BLOCK)  // 256000/1024 = 250 exactly

typedef float v4f __attribute__((ext_vector_type(4)));

__global__ __launch_bounds__(BLOCK) void ola_gather_kernel(
    const float* __restrict__ x, float* __restrict__ out)
{
    const int b = blockIdx.y;
    const float* __restrict__ xb = x + (size_t)b * IN_PER_B;
    float* __restrict__ ob = out + (size_t)b * OUT_PER_B;

    const int g0 = blockIdx.x * GROUPS_PER_BLOCK + threadIdx.x;

    // Block's q range: [8*bx+1, 8*bx+9]; interior needs q>=3 and q<=NFV-1.
    const bool interior = (blockIdx.x >= 1) & (blockIdx.x <= GRID_X - 2);

    if (interior) {
        v4f v[ITERS][4];
        const float* base[ITERS];
#pragma unroll
        for (int it = 0; it < ITERS; ++it) {
            const int o = (g0 + it * BLOCK) * 4;
            const int p = o + PAD0;
            const int q = p >> 9;
            const int r = p & 511;
            base[it] = xb + ((size_t)q << 11) + r;          // f=q, t=r
        }
        // Issue all 16 loads back-to-back (f = q-j -> base - 1536*j floats).
#pragma unroll
        for (int it = 0; it < ITERS; ++it) {
#pragma unroll
            for (int j = 0; j < 4; ++j)
                v[it][j] = *(const v4f*)(base[it] - 1536 * j);
        }
#pragma unroll
        for (int it = 0; it < ITERS; ++it) {
            const int o = (g0 + it * BLOCK) * 4;
            v4f s = (v[it][0] + v[it][1] + v[it][2] + v[it][3]) * 0.25f;
            __builtin_nontemporal_store(s, (v4f*)(ob + o));
        }
    } else {
        for (int it = 0; it < ITERS; ++it) {
            const int o = (g0 + it * BLOCK) * 4;
            const int p = o + PAD0;
            const int q = p >> 9;
            v4f acc = {0.f, 0.f, 0.f, 0.f};
            int cnt = 0;
#pragma unroll
            for (int j = 0; j < 4; ++j) {
                const int f = q - j;
                if (f >= 0 && f < NFV) {
                    const int t = p - (f << 9);
                    const v4f v = *(const v4f*)(xb + (size_t)f * FRAME + t);
                    acc += v;
                    ++cnt;
                }
            }
            const float sc = 1.0f / (float)cnt;
            *(v4f*)(ob + o) = acc * sc;
        }
    }
}

extern "C" void kernel_launch(void* const* d_in, const int* in_sizes, int n_in,
                              void* d_out, int out_size, void* d_ws, size_t ws_size,
                              hipStream_t stream)
{
    const float* x = (const float*)d_in[0];
    float* out = (float*)d_out;

    const int B = in_sizes[0] / IN_PER_B;                   // 16
    dim3 grid(GRID_X, B);
    ola_gather_kernel<<<grid, dim3(BLOCK), 0, stream>>>(x, out);
}

// Round 4
// 348.644 us; speedup vs baseline: 1.0742x; 1.0742x over previous
//
#include <hip/hip_runtime.h>

// Overlap-add reconstruction (inverse framing), MI355X / gfx950. Round 4.
//
// x: [B=16, FV=2000, FRAME=2048] fp32, HOP=512, PAD0=PAD1=768.
// out[b][o] = (1/cnt) * sum_f x[b][f][p-512f], p=o+PAD0, q=p>>9,
//   f in [max(0,q-3), min(FV-1,q)]. Irreducible traffic 256 MB R + 64 MB W.
//
// History: R1 plain ld/st ~105us | R2 nt ld+st, ITERS=2 ~95us (BEST)
//          R3 plain ld + nt st, ITERS=4 ~124us (REGRESS -> nt loads matter;
//          waves*MLP was constant so ITERS=4 itself not implicated).
// R4 = R3 structure + nt loads restored (single controlled change vs R2:
//      MLP 8 -> 16 loads in flight/thread). Also: base[it] = base0 + 4096*it
//      (q advances exactly 2 per iteration), one base calc per thread.

#define FRAME   2048
#define HOP     512
#define NFV     2000
#define PAD0    768
#define OUT_PER_B (NFV * HOP)          // 1,024,000
#define IN_PER_B  (NFV * FRAME)        // 4,096,000
#define BLOCK   256
#define ITERS   4
#define GROUPS_PER_BLOCK (BLOCK * ITERS)            // 1024 groups = 4096 samples
#define GRID_X  (OUT_PER_B / 4 / GROUPS_PER_BLOCK)  // 250 exactly

typedef float v4f __attribute__((ext_vector_type(4)));

__global__ __launch_bounds__(BLOCK) void ola_gather_kernel(
    const float* __restrict__ x, float* __restrict__ out)
{
    const int b = blockIdx.y;
    const float* __restrict__ xb = x + (size_t)b * IN_PER_B;
    float* __restrict__ ob = out + (size_t)b * OUT_PER_B;

    const int g0 = blockIdx.x * GROUPS_PER_BLOCK + threadIdx.x;

    // Block's q range: [8*bx+1, 8*bx+9]; interior needs q>=3 and q<=NFV-1.
    const bool interior = (blockIdx.x >= 1) & (blockIdx.x <= GRID_X - 2);

    if (interior) {
        const int o0 = g0 * 4;
        const int p0 = o0 + PAD0;
        const int q0 = p0 >> 9;
        const int r0 = p0 & 511;
        const float* base0 = xb + ((size_t)q0 << 11) + r0;  // f=q0, t=r0

        v4f v[ITERS][4];
        // Issue all 16 nt loads back-to-back.
        // iteration step: o += 1024 -> q += 2 -> base += 4096 floats.
        // stream step:    f = q-j   -> addr = base - 1536*j floats.
#pragma unroll
        for (int it = 0; it < ITERS; ++it) {
            const float* base = base0 + 4096 * it;
#pragma unroll
            for (int j = 0; j < 4; ++j)
                v[it][j] = __builtin_nontemporal_load((const v4f*)(base - 1536 * j));
        }
#pragma unroll
        for (int it = 0; it < ITERS; ++it) {
            v4f s = (v[it][0] + v[it][1] + v[it][2] + v[it][3]) * 0.25f;
            __builtin_nontemporal_store(s, (v4f*)(ob + o0 + it * (BLOCK * 4)));
        }
    } else {
        for (int it = 0; it < ITERS; ++it) {
            const int o = (g0 + it * BLOCK) * 4;
            const int p = o + PAD0;
            const int q = p >> 9;
            v4f acc = {0.f, 0.f, 0.f, 0.f};
            int cnt = 0;
#pragma unroll
            for (int j = 0; j < 4; ++j) {
                const int f = q - j;
                if (f >= 0 && f < NFV) {
                    const int t = p - (f << 9);
                    const v4f v = *(const v4f*)(xb + (size_t)f * FRAME + t);
                    acc += v;
                    ++cnt;
                }
            }
            const float sc = 1.0f / (float)cnt;
            *(v4f*)(ob + o) = acc * sc;
        }
    }
}

extern "C" void kernel_launch(void* const* d_in, const int* in_sizes, int n_in,
                              void* d_out, int out_size, void* d_ws, size_t ws_size,
                              hipStream_t stream)
{
    const float* x = (const float*)d_in[0];
    float* out = (float*)d_out;

    const int B = in_sizes[0] / IN_PER_B;                   // 16
    dim3 grid(GRID_X, B);
    ola_gather_kernel<<<grid, dim3(BLOCK), 0, stream>>>(x, out);
}